// Round 1
// 433.156 us; speedup vs baseline: 1.0322x; 1.0322x over previous
//
#include <hip/hip_runtime.h>
#include <math.h>

// ---- problem constants ----
#define TB        256           // threads per block = 4 waves
#define POSB      128           // positions per block (2 per lane)  [R7: was 64]
#define GROUPS    4             // K-split: wave g scans codes [g*KPG,(g+1)*KPG)
#define KPG       128           // codes per group
#define NPOS      131072        // B*H*W positions
#define KCODES    512
#define DIM       64
#define HW        4096          // H*W
#define LOSS_OFF  8388608ull
#define ENC_OFF   8388609ull
#define PERP_OFF  75497473ull
#define TILE_DW   (POSB * KCODES)       // 65536 dwords: block's encodings tile
#define NF4       ((TILE_DW - 4) / 4)   // 16383 float4 after the +3 align shift

__device__ __forceinline__ float tree8(float r0, float r1, float r2, float r3,
                                       float r4, float r5, float r6, float r7) {
    // numpy pairwise combine: ((r0+r1)+(r2+r3)) + ((r4+r5)+(r6+r7))
    return __fadd_rn(__fadd_rn(__fadd_rn(r0, r1), __fadd_rn(r2, r3)),
                     __fadd_rn(__fadd_rn(r4, r5), __fadd_rn(r6, r7)));
}

// Prep: ww[k] = sum(w[k]^2) in numpy pairwise order; zero counts + loss accumulator.
extern "C" __global__ __launch_bounds__(512)
void vq_prep(const float* __restrict__ w, float* __restrict__ ww,
             int* __restrict__ counts, float* __restrict__ lossAcc)
{
    const int k = threadIdx.x;                 // 512 threads
    const float* wk = w + k * DIM;
    float r[8];
    #pragma unroll
    for (int i = 0; i < 8; ++i) {
        #pragma unroll
        for (int j = 0; j < 8; ++j) {
            float v = wk[i * 8 + j];
            float pp = __fmul_rn(v, v);
            r[j] = (i == 0) ? pp : __fadd_rn(r[j], pp);
        }
    }
    ww[k] = tree8(r[0], r[1], r[2], r[3], r[4], r[5], r[6], r[7]);
    counts[k] = 0;
    if (k == 0) *lossAcc = 0.0f;
}

// R7: 2 positions per lane. R6's loop exposed ~200-250cy of scalar-cache/L2
// latency per 256B w-row s_load against only 128 FMA cycles (no SGPR room to
// double-buffer a 64-dword row). Holding x2 for TWO positions (128 VGPRs)
// amortizes each row fetch over 256 FMA cycles, halving scalar-fetch pressure
// per FLOP. ~170 VGPR -> waves_per_eu(2,2) (budget 256, no spill); grid 1024
// blocks = 4 waves/SIMD queued, 2 resident. Exact numpy pairwise order kept
// per position -> argmin bit-identical to R6.
#define EPILOGUE(X2, P)  do {                                                   \
    const int p_ = (P);                                                         \
    float fb = cdist[0][p_];                                                    \
    int   fk = ckidx[0][p_];                                                    \
    _Pragma("unroll")                                                           \
    for (int gg = 1; gg < GROUPS; ++gg) {                                       \
        float dg = cdist[gg][p_];                                               \
        int   kg = ckidx[gg][p_];                                               \
        if (dg < fb) { fb = dg; fk = kg; }                                      \
    }                                                                           \
    out[ENC_OFF + (size_t)(blockIdx.x * POSB + p_) * KCODES + fk] = 1.0f;       \
    atomicAdd(&hcount[fk], 1);                                                  \
    const float4* wrow = reinterpret_cast<const float4*>(w + (size_t)fk * DIM); \
    float* qo = out + ((size_t)b * DIM) * HW + (hwb + p_);                      \
    float sse = 0.0f;                                                           \
    _Pragma("unroll")                                                           \
    for (int c = 0; c < 16; ++c) {                                              \
        float4 q = wrow[c];                                                     \
        qo[(size_t)(4 * c + 0) * HW] = q.x;                                     \
        qo[(size_t)(4 * c + 1) * HW] = q.y;                                     \
        qo[(size_t)(4 * c + 2) * HW] = q.z;                                     \
        qo[(size_t)(4 * c + 3) * HW] = q.w;                                     \
        float e0 = q.x - 0.5f * X2[4 * c + 0]; sse = __fmaf_rn(e0, e0, sse);    \
        float e1 = q.y - 0.5f * X2[4 * c + 1]; sse = __fmaf_rn(e1, e1, sse);    \
        float e2 = q.z - 0.5f * X2[4 * c + 2]; sse = __fmaf_rn(e2, e2, sse);    \
        float e3 = q.w - 0.5f * X2[4 * c + 3]; sse = __fmaf_rn(e3, e3, sse);    \
    }                                                                           \
    _Pragma("unroll")                                                           \
    for (int off = 32; off > 0; off >>= 1) sse += __shfl_down(sse, off);        \
    if (l == 0) atomicAdd(lossAcc, sse);                                        \
} while (0)

extern "C" __global__ __launch_bounds__(TB)
__attribute__((amdgpu_waves_per_eu(2, 2)))
void vq_main(const float* __restrict__ x, const float* __restrict__ w,
             const float* __restrict__ ww, float* __restrict__ out,
             int* __restrict__ counts, float* __restrict__ lossAcc)
{
    __shared__ float cdist[GROUPS][POSB];
    __shared__ int   ckidx[GROUPS][POSB];
    __shared__ int   hcount[KCODES];

    const int tid = threadIdx.x;
    const int l   = tid & 63;                                  // lane
    const int g   = __builtin_amdgcn_readfirstlane(tid >> 6);  // wave id, uniform
    const int hwb = (blockIdx.x * POSB) & 4095;                // 128 | 4096: one b/block
    const int b   = (blockIdx.x * POSB) >> 12;

    hcount[tid]      = 0;
    hcount[tid + TB] = 0;

    // ---- prologue: TWO positions' x into VGPRs (channel stride HW); x2 = 2x;
    // A = pairwise_sum(x^2). All 4 waves load the same 32KB slice -> L1 hits.
    const float* xp = x + ((size_t)b * DIM) * HW + (hwb + l);
    float x2a[DIM], x2b[DIM];
    float A0, A1;
    {
        float ra[8], rb[8];
        #pragma unroll
        for (int i = 0; i < 8; ++i) {
            #pragma unroll
            for (int j = 0; j < 8; ++j) {
                const int d = i * 8 + j;
                float va = xp[(size_t)d * HW];
                float vb = xp[(size_t)d * HW + 64];
                x2a[d] = va + va;                   // exact doubling
                x2b[d] = vb + vb;
                float pa = __fmul_rn(va, va);
                float pb = __fmul_rn(vb, vb);
                ra[j] = (i == 0) ? pa : __fadd_rn(ra[j], pa);
                rb[j] = (i == 0) ? pb : __fadd_rn(rb[j], pb);
            }
        }
        A0 = tree8(ra[0], ra[1], ra[2], ra[3], ra[4], ra[5], ra[6], ra[7]);
        A1 = tree8(rb[0], rb[1], rb[2], rb[3], rb[4], rb[5], rb[6], rb[7]);
    }

    // ---- scan my 128-code group for both positions; interleave coalesced
    // float4 zero-fill of the block's 128x512-dword encodings tile
    // (T0%4==1, dwords 3+4m aligned; one float4 per thread every 2nd iter).
    float best0 = INFINITY, best1 = INFINITY;
    int   bk0 = 0, bk1 = 0;
    const size_t T0 = ENC_OFF + (size_t)blockIdx.x * TILE_DW;
    float4* zs4 = reinterpret_cast<float4*>(out + T0 + 3);
    const float4 zero4 = make_float4(0.0f, 0.0f, 0.0f, 0.0f);

    for (int kk = 0; kk < KPG; ++kk) {
        const int k = g * KPG + kk;             // wave-uniform -> s_load path
        const float* wk = w + (size_t)k * DIM;
        float s0[8], s1[8];
        #pragma unroll
        for (int i = 0; i < 8; ++i) {
            #pragma unroll
            for (int j = 0; j < 8; ++j) {
                const int d = i * 8 + j;
                float wv = wk[d];               // 1 SGPR operand per FMA
                if (i == 0) {
                    s0[j] = __fmul_rn(x2a[d], wv);
                    s1[j] = __fmul_rn(x2b[d], wv);
                } else {
                    s0[j] = __fmaf_rn(x2a[d], wv, s0[j]);
                    s1[j] = __fmaf_rn(x2b[d], wv, s1[j]);
                }
            }
        }
        float dot0 = tree8(s0[0], s0[1], s0[2], s0[3], s0[4], s0[5], s0[6], s0[7]);
        float dot1 = tree8(s1[0], s1[1], s1[2], s1[3], s1[4], s1[5], s1[6], s1[7]);
        float wwk  = ww[k];                     // wave-uniform s_load
        float t0s  = __fadd_rn(A0, wwk);        // (||x||^2 + ||w_k||^2), ref order
        float t1s  = __fadd_rn(A1, wwk);
        float d0   = __fadd_rn(t0s, -dot0);     // minus 2*x.w
        float d1   = __fadd_rn(t1s, -dot1);
        if (d0 < best0) { best0 = d0; bk0 = k; }
        if (d1 < best1) { best1 = d1; bk1 = k; }

        if ((kk & 1) == 0) {                    // 64 float4 per thread total
            const int m = (kk >> 1) * TB + tid; // [0, 16384)
            if (m < NF4) zs4[m] = zero4;        // m=16383 crosses tile edge
        }
    }
    cdist[g][l]      = best0;
    ckidx[g][l]      = bk0;
    cdist[g][l + 64] = best1;
    ckidx[g][l + 64] = bk1;

    // edge dwords of the tile (not covered by the float4 sweep)
    if (tid < 3)  out[T0 + tid] = 0.0f;              // d = 0,1,2
    if (tid == 3) out[T0 + (TILE_DW - 1)] = 0.0f;    // d = 65535

    __syncthreads();   // zero stores drained (vmcnt(0) at barrier); candidates visible

    // ---- merge 4 candidates + epilogue: waves 0 and 1 each own 64 positions
    // (constant x2 indices via macro; avoids dynamic-index scratch).
    if (g == 0)      { EPILOGUE(x2a, l); }
    else if (g == 1) { EPILOGUE(x2b, l + 64); }

    __syncthreads();   // waves 0/1's hcount atomics done

    // histogram drain
    {
        int c0 = hcount[tid];       if (c0) atomicAdd(&counts[tid], c0);
        int c1 = hcount[tid + TB];  if (c1) atomicAdd(&counts[tid + TB], c1);
    }
}

// Finalize: loss scalar + perplexity from histogram.
extern "C" __global__ __launch_bounds__(512)
void vq_finalize(const int* __restrict__ counts, const float* __restrict__ lossAcc,
                 float* __restrict__ out)
{
    __shared__ double sred[KCODES];
    const int t = threadIdx.x;                 // 512 threads
    double p = (double)counts[t] * (1.0 / (double)NPOS);
    sred[t] = -p * log(p + 1e-10);
    __syncthreads();
    for (int s = KCODES / 2; s > 0; s >>= 1) {
        if (t < s) sred[t] += sred[t + s];
        __syncthreads();
    }
    if (t == 0) {
        out[PERP_OFF] = (float)exp(sred[0]);
        out[LOSS_OFF] = 1.25f * (lossAcc[0] / 8388608.0f);
    }
}

extern "C" void kernel_launch(void* const* d_in, const int* in_sizes, int n_in,
                              void* d_out, int out_size, void* d_ws, size_t ws_size,
                              hipStream_t stream)
{
    const float* x = (const float*)d_in[0];    // [32,64,64,64] fp32
    const float* w = (const float*)d_in[1];    // [512,64] fp32
    float* out = (float*)d_out;

    float* ww      = (float*)d_ws;                         // 512 floats
    int*   counts  = (int*)((char*)d_ws + 2048);           // 512 ints
    float* lossAcc = (float*)((char*)d_ws + 4096);         // 1 float

    vq_prep<<<1, 512, 0, stream>>>(w, ww, counts, lossAcc);
    vq_main<<<NPOS / POSB, TB, 0, stream>>>(x, w, ww, out, counts, lossAcc);
    vq_finalize<<<1, 512, 0, stream>>>(counts, lossAcc, out);
}